// Round 17
// baseline (107.702 us; speedup 1.0000x reference)
//
#include <hip/hip_runtime.h>

#define D_MODEL 1024
#define SEQ     2048
#define BATCH   2
#define NH      16

using u16 = unsigned short;
typedef __bf16 bf16x8 __attribute__((ext_vector_type(8)));
typedef float  f32x4  __attribute__((ext_vector_type(4)));

__device__ __forceinline__ u16 f2bf(float f){
  union { __bf16 h; u16 u; } v; v.h = (__bf16)f; return v.u;
}

__device__ __forceinline__ void gload_lds16(const void* g, void* l){
  __builtin_amdgcn_global_load_lds(
      (const __attribute__((address_space(1))) void*)g,
      (__attribute__((address_space(3))) void*)l, 16, 0, 0);
}

// ---------- kernel 1+2 merged: X fp32->bf16  AND  weights ->bf16 [N][K] ----
__global__ __launch_bounds__(256) void k_prep(
    const float* __restrict__ X, u16* __restrict__ Xb,
    const float* __restrict__ wq, const float* __restrict__ wk,
    const float* __restrict__ wv, const float* __restrict__ w0,
    u16* __restrict__ oq, u16* __restrict__ ok,
    u16* __restrict__ ov, u16* __restrict__ o0)
{
  const int t = threadIdx.x;
  if (blockIdx.x < 4096){
    int i = blockIdx.x*256 + t;
    float4 v = ((const float4*)X)[i];
    ushort4 o; o.x=f2bf(v.x); o.y=f2bf(v.y); o.z=f2bf(v.z); o.w=f2bf(v.w);
    ((ushort4*)Xb)[i] = o;
    return;
  }
  const int bid = blockIdx.x - 4096;
  const int z = bid >> 8, rem = bid & 255;
  const int nt = (rem & 15)*64, kt = (rem >> 4)*64;
  const float* W; u16* O;
  if      (z==0){W=wq;O=oq;}
  else if (z==1){W=wk;O=ok;}
  else if (z==2){W=wv;O=ov;}
  else          {W=w0;O=o0;}
  __shared__ float T[64][65];
  int r0 = t>>4, cb = (t&15)*4;
  #pragma unroll
  for (int j=0;j<4;++j){
    int r = r0 + j*16;
    float4 v = *(const float4*)(W + (size_t)(kt + r)*1024 + nt + cb);
    T[r][cb] = v.x; T[r][cb+1] = v.y; T[r][cb+2] = v.z; T[r][cb+3] = v.w;
  }
  __syncthreads();
  #pragma unroll
  for (int j=0;j<4;++j){
    int rn = r0 + j*16;
    ushort4 o;
    o.x = f2bf(T[cb  ][rn]); o.y = f2bf(T[cb+1][rn]);
    o.z = f2bf(T[cb+2][rn]); o.w = f2bf(T[cb+3][rn]);
    *(ushort4*)(O + (size_t)(nt + rn)*1024 + kt + cb) = o;
  }
}

// ---------- kernel 3: fused QKV GEMM (2-phase dbuf; V fused to Vt) ---------
// At 645 TF this kernel sits AT the measured 2-phase K=1024 structure
// ceiling (m248v2: 655-666 TF). 8-phase 256^2 is shape-mismatched (192
// blocks < 256 CUs); counted-vmcnt graft regressed (R12). Keep.
__global__ __launch_bounds__(256) void k_gemm_qkv(
    const u16* __restrict__ A, const u16* __restrict__ Bt,
    u16* __restrict__ Ob, u16* __restrict__ Vt, float scaleQ)
{
  const int K = 1024, N = 3072;
  const int nwg = gridDim.x * gridDim.y;
  const int f = blockIdx.y * gridDim.x + blockIdx.x;
  const int sw = (f & 7) * (nwg >> 3) + (f >> 3);
  const int bxs = sw % gridDim.x, bys = sw / gridDim.x;
  const int bm = bys*128, bn = bxs*128;
  const float scl = (bn < 1024) ? scaleQ : 1.0f;
  const int lane = threadIdx.x & 63, w = threadIdx.x >> 6;
  const int hi = lane >> 4, c = lane & 15;
  const int wr = w >> 1, wc = w & 1;

  __shared__ u16 As[2][128*32];
  __shared__ u16 Bs[2][128*32];

  const int i0 = 2*w, i1 = 2*w+1;
  const int rA0 = i0*16 + (lane>>2), rA1 = i1*16 + (lane>>2);
  const int cA  = (lane&3)*8;
  const u16* aS0 = A  + (size_t)(bm + rA0)*K + cA;
  const u16* aS1 = A  + (size_t)(bm + rA1)*K + cA;
  const u16* bS0 = Bt + (size_t)(bn + rA0)*K + cA;
  const u16* bS1 = Bt + (size_t)(bn + rA1)*K + cA;

  auto stage = [&](int buf, int kk){
    gload_lds16(aS0 + kk, As[buf] + i0*512);
    gload_lds16(aS1 + kk, As[buf] + i1*512);
    gload_lds16(bS0 + kk, Bs[buf] + i0*512);
    gload_lds16(bS1 + kk, Bs[buf] + i1*512);
  };

  f32x4 acc[4][4];
  #pragma unroll
  for (int mi=0;mi<4;++mi)
    #pragma unroll
    for (int ni=0;ni<4;++ni) acc[mi][ni] = (f32x4){0.f,0.f,0.f,0.f};

  stage(0, 0);
  __syncthreads();
  int cur = 0;
  for (int kk = 0; kk < K; kk += 32){
    if (kk + 32 < K) stage(cur^1, kk + 32);
    const u16* as = As[cur];
    const u16* bs = Bs[cur];
    bf16x8 af[4], bfr[4];
    #pragma unroll
    for (int mi=0;mi<4;++mi)
      af[mi] = *(const bf16x8*)(as + (wr*64 + mi*16 + c)*32 + hi*8);
    #pragma unroll
    for (int ni=0;ni<4;++ni)
      bfr[ni] = *(const bf16x8*)(bs + (wc*64 + ni*16 + c)*32 + hi*8);
    #pragma unroll
    for (int mi=0;mi<4;++mi)
      #pragma unroll
      for (int ni=0;ni<4;++ni)
        acc[mi][ni] = __builtin_amdgcn_mfma_f32_16x16x32_bf16(af[mi], bfr[ni], acc[mi][ni], 0, 0, 0);
    __syncthreads();
    cur ^= 1;
  }

  if (bn < 2048){
    #pragma unroll
    for (int mi=0;mi<4;++mi){
      #pragma unroll
      for (int ni=0;ni<4;++ni){
        int row = bm + wr*64 + mi*16 + hi*4;
        int col = bn + wc*64 + ni*16 + c;
        #pragma unroll
        for (int r=0;r<4;++r)
          Ob[(size_t)(row + r)*N + col] = f2bf(acc[mi][ni][r] * scl);
      }
    }
  } else {
    // V columns: fused transpose + key-permute into Vt [B*H][64][S-perm]
    #pragma unroll
    for (int mi=0;mi<4;++mi){
      int row = bm + wr*64 + mi*16 + hi*4;           // token s (4-aligned)
      int b_  = row >> 11, s_ = row & 2047;
      int st  = s_ >> 6,  sl = s_ & 63;
      int p   = (sl & 0x23) | ((sl & 0x10) >> 2) | ((sl & 0x0C) << 1);
      #pragma unroll
      for (int ni=0;ni<4;++ni){
        int col = (bn - 2048) + wc*64 + ni*16 + c;    // d_full in [0,1024)
        int h_ = col >> 6, d_ = col & 63;
        u16* dst = Vt + ((size_t)(b_*16 + h_)*64 + d_)*SEQ + st*64 + p;
        ushort4 o;
        o.x = f2bf(acc[mi][ni][0]); o.y = f2bf(acc[mi][ni][1]);
        o.z = f2bf(acc[mi][ni][2]); o.w = f2bf(acc[mi][ni][3]);
        *(ushort4*)dst = o;
      }
    }
  }
}

// ---------- kernel 6: out-proj GEMM -- 64x128 tile, 2 blocks/CU ------------
// R16 isolated change: at 128^2 the grid is 256 blocks = exactly 1 block/CU,
// so the 2-phase barrier drain has no co-resident block to overlap it.
// 64x128 -> 512 blocks = 2/CU (XCD swizzle, nwg=512 %8==0).
__global__ __launch_bounds__(256) void k_gemm_out(
    const u16* __restrict__ A, const u16* __restrict__ Bt,
    float* __restrict__ OF)
{
  const int K = 1024, N = 1024;
  const int nwg = gridDim.x * gridDim.y;
  const int f = blockIdx.y * gridDim.x + blockIdx.x;
  const int sw = (f & 7) * (nwg >> 3) + (f >> 3);
  const int bxs = sw % gridDim.x, bys = sw / gridDim.x;
  const int bm = bys*64, bn = bxs*128;
  const int lane = threadIdx.x & 63, w = threadIdx.x >> 6;
  const int hi = lane >> 4, c = lane & 15;
  const int wr = w >> 1, wc = w & 1;

  __shared__ u16 As[2][64*32];
  __shared__ u16 Bs[2][128*32];

  const int i0 = 2*w, i1 = 2*w+1;
  const int cA = (lane&3)*8;
  const u16* aS  = A  + (size_t)(bm + w*16  + (lane>>2))*K + cA;
  const u16* bS0 = Bt + (size_t)(bn + i0*16 + (lane>>2))*K + cA;
  const u16* bS1 = Bt + (size_t)(bn + i1*16 + (lane>>2))*K + cA;

  auto stage = [&](int buf, int kk){
    gload_lds16(aS  + kk, As[buf] + w*512);
    gload_lds16(bS0 + kk, Bs[buf] + i0*512);
    gload_lds16(bS1 + kk, Bs[buf] + i1*512);
  };

  f32x4 acc[2][4];
  #pragma unroll
  for (int mi=0;mi<2;++mi)
    #pragma unroll
    for (int ni=0;ni<4;++ni) acc[mi][ni] = (f32x4){0.f,0.f,0.f,0.f};

  stage(0, 0);
  __syncthreads();
  int cur = 0;
  for (int kk = 0; kk < K; kk += 32){
    if (kk + 32 < K) stage(cur^1, kk + 32);
    const u16* as = As[cur];
    const u16* bs = Bs[cur];
    bf16x8 af[2], bfr[4];
    #pragma unroll
    for (int mi=0;mi<2;++mi)
      af[mi] = *(const bf16x8*)(as + (wr*32 + mi*16 + c)*32 + hi*8);
    #pragma unroll
    for (int ni=0;ni<4;++ni)
      bfr[ni] = *(const bf16x8*)(bs + (wc*64 + ni*16 + c)*32 + hi*8);
    #pragma unroll
    for (int mi=0;mi<2;++mi)
      #pragma unroll
      for (int ni=0;ni<4;++ni)
        acc[mi][ni] = __builtin_amdgcn_mfma_f32_16x16x32_bf16(af[mi], bfr[ni], acc[mi][ni], 0, 0, 0);
    __syncthreads();
    cur ^= 1;
  }
  #pragma unroll
  for (int mi=0;mi<2;++mi){
    #pragma unroll
    for (int ni=0;ni<4;++ni){
      int row = bm + wr*32 + mi*16 + hi*4;
      int col = bn + wc*64 + ni*16 + c;
      #pragma unroll
      for (int r=0;r<4;++r)
        OF[(size_t)(row + r)*N + col] = acc[mi][ni][r];
    }
  }
}

// ---------- kernel 5: attention (R13 structure -- best measured) -----------
// 4 waves/block (256 thr) = 2 qg x 2 kh; 64 q-rows per wave (4 qsub x 16).
// R14: direct-L2 K/V regressed (LDS staging IS coalescing). R15: 2-wave
// blocks regressed (VGPR 148). grid (bh, qt) head-affine; SWAPPED QK^T;
// exp2 packed as 16x16x32 A-frag; Vt pre-permuted; lsum via ones-MFMA.
__global__ __launch_bounds__(256, 2) void k_attn(const u16* __restrict__ QKV,
                                                 const u16* __restrict__ Vt,
                                                 u16* __restrict__ AO)
{
  const int bh = blockIdx.x, qt = blockIdx.y;
  const int b = bh >> 4, h = bh & 15;
  const int lane = threadIdx.x & 63, w = threadIdx.x >> 6;  // w = 0..3
  const int qg = w >> 1, kh = w & 1;
  const int hi = lane >> 4, c = lane & 15;

  __shared__ u16 Ks[2][64*64];   // [key][dim] rows 128B, source-swizzled
  __shared__ u16 Vs[2][64*64];   // [dim][key'] rows 128B, source-swizzled

  const size_t qrow0 = (size_t)(b*SEQ + qt*128 + qg*64 + c);
  bf16x8 qf0[4], qf1[4];
  #pragma unroll
  for (int s=0;s<4;++s){
    qf0[s] = *(const bf16x8*)(QKV + (qrow0 + s*16)*3072 + h*64 + hi*8);
    qf1[s] = *(const bf16x8*)(QKV + (qrow0 + s*16)*3072 + h*64 + 32 + hi*8);
  }

  bf16x8 ones8;
  #pragma unroll
  for (int j=0;j<8;++j) ones8[j] = (__bf16)1.0f;

  f32x4 acc_o[4][4];
  f32x4 acc_l[4];
  #pragma unroll
  for (int s=0;s<4;++s){
    acc_l[s] = (f32x4){0.f,0.f,0.f,0.f};
    #pragma unroll
    for (int n=0;n<4;++n) acc_o[s][n] = (f32x4){0.f,0.f,0.f,0.f};
  }

  // staging: wave w stages rows w*8..+7 (instr0) and 32+w*8..+7 (instr1)
  const int r0 = w*8 + (lane>>3);
  const int r1 = 32 + r0;
  const int sb = ((((lane&7)*16) ^ ((lane>>3)<<4)) >> 1);  // u16 units
  const u16* kS0 = QKV + (size_t)(b*SEQ + r0)*3072 + 1024 + h*64 + sb;
  const u16* kS1 = QKV + (size_t)(b*SEQ + r1)*3072 + 1024 + h*64 + sb;
  const u16* vS0 = Vt + ((size_t)bh*64 + r0)*SEQ + sb;
  const u16* vS1 = Vt + ((size_t)bh*64 + r1)*SEQ + sb;

  auto stage = [&](int buf){
    gload_lds16(kS0, Ks[buf] + w*512);
    gload_lds16(kS1, Ks[buf] + 2048 + w*512);
    gload_lds16(vS0, Vs[buf] + w*512);
    gload_lds16(vS1, Vs[buf] + 2048 + w*512);
    kS0 += (size_t)64*3072; kS1 += (size_t)64*3072; vS0 += 64; vS1 += 64;
  };

  // hoisted LDS read bases; XOR applied to full byte-within-row offset
  const int swz = ((c&7)<<4);
  const char* kr0 = (const char*)&Ks[0][0] + (kh*32 + c)*128 + (( 0 + hi*16) ^ swz);
  const char* kr1 = (const char*)&Ks[0][0] + (kh*32 + c)*128 + ((64 + hi*16) ^ swz);
  const char* vr  = (const char*)&Vs[0][0] + c*128 + ((kh*64 + hi*16) ^ swz);

  auto body = [&](int buf){
    const int bo = buf*8192;
    bf16x8 k00 = *(const bf16x8*)(kr0 + bo);          // keys t0, dims 0-31
    bf16x8 k01 = *(const bf16x8*)(kr1 + bo);          // keys t0, dims 32-63
    bf16x8 k10 = *(const bf16x8*)(kr0 + bo + 2048);   // keys t1, dims 0-31
    bf16x8 k11 = *(const bf16x8*)(kr1 + bo + 2048);   // keys t1, dims 32-63
    bf16x8 vv0 = *(const bf16x8*)(vr + bo);
    bf16x8 vv1 = *(const bf16x8*)(vr + bo + 2048);
    bf16x8 vv2 = *(const bf16x8*)(vr + bo + 4096);
    bf16x8 vv3 = *(const bf16x8*)(vr + bo + 6144);
    #pragma unroll
    for (int s=0;s<4;++s){
      f32x4 s0 = (f32x4){0.f,0.f,0.f,0.f};
      f32x4 s1 = (f32x4){0.f,0.f,0.f,0.f};
      __builtin_amdgcn_s_setprio(1);
      s0 = __builtin_amdgcn_mfma_f32_16x16x32_bf16(k00, qf0[s], s0, 0,0,0);
      s1 = __builtin_amdgcn_mfma_f32_16x16x32_bf16(k10, qf0[s], s1, 0,0,0);
      s0 = __builtin_amdgcn_mfma_f32_16x16x32_bf16(k01, qf1[s], s0, 0,0,0);
      s1 = __builtin_amdgcn_mfma_f32_16x16x32_bf16(k11, qf1[s], s1, 0,0,0);
      __builtin_amdgcn_s_setprio(0);
      bf16x8 a;
      #pragma unroll
      for (int i=0;i<4;++i){
        a[i]   = (__bf16)__builtin_amdgcn_exp2f(s0[i]);
        a[i+4] = (__bf16)__builtin_amdgcn_exp2f(s1[i]);
      }
      __builtin_amdgcn_s_setprio(1);
      acc_l[s]    = __builtin_amdgcn_mfma_f32_16x16x32_bf16(a, ones8, acc_l[s], 0,0,0);
      acc_o[s][0] = __builtin_amdgcn_mfma_f32_16x16x32_bf16(a, vv0, acc_o[s][0], 0,0,0);
      acc_o[s][1] = __builtin_amdgcn_mfma_f32_16x16x32_bf16(a, vv1, acc_o[s][1], 0,0,0);
      acc_o[s][2] = __builtin_amdgcn_mfma_f32_16x16x32_bf16(a, vv2, acc_o[s][2], 0,0,0);
      acc_o[s][3] = __builtin_amdgcn_mfma_f32_16x16x32_bf16(a, vv3, acc_o[s][3], 0,0,0);
      __builtin_amdgcn_s_setprio(0);
    }
  };

  stage(0);
  __syncthreads();
  #pragma unroll 1
  for (int u = 0; u < SEQ/128; ++u){
    stage(1);
    body(0);
    __syncthreads();
    if (u != SEQ/128 - 1) stage(0);
    body(1);
    __syncthreads();
  }

  // merge key-halves additively, one qsub pass at a time (Of = 8KB in Ks)
  float* Of = (float*)&Ks[0][0];           // [qg][16][64] f32
  float* Lf = (float*)&Vs[0][0];           // [qg][16]
  #pragma unroll
  for (int s=0;s<4;++s){
    if (kh == 1){
      #pragma unroll
      for (int n=0;n<4;++n)
        #pragma unroll
        for (int i=0;i<4;++i)
          Of[qg*1024 + (hi*4+i)*64 + n*16 + c] = acc_o[s][n][i];
      if (c == 0){
        #pragma unroll
        for (int i=0;i<4;++i) Lf[qg*16 + hi*4 + i] = acc_l[s][i];
      }
    }
    __syncthreads();
    if (kh == 0){
      float inv[4];
      #pragma unroll
      for (int i=0;i<4;++i)
        inv[i] = 1.0f / (acc_l[s][i] + Lf[qg*16 + hi*4 + i]);
      size_t obase = (size_t)(b*SEQ + qt*128 + qg*64 + s*16 + hi*4)*D_MODEL + h*64;
      #pragma unroll
      for (int i=0;i<4;++i){
        #pragma unroll
        for (int n=0;n<4;++n){
          float o = acc_o[s][n][i] + Of[qg*1024 + (hi*4+i)*64 + n*16 + c];
          AO[obase + (size_t)i*D_MODEL + n*16 + c] = f2bf(o * inv[i]);
        }
      }
    }
    __syncthreads();
  }
}

extern "C" void kernel_launch(void* const* d_in, const int* in_sizes, int n_in,
                              void* d_out, int out_size, void* d_ws, size_t ws_size,
                              hipStream_t stream)
{
  const float* X  = (const float*)d_in[0];
  const float* Wq = (const float*)d_in[1];
  const float* Wk = (const float*)d_in[2];
  const float* Wv = (const float*)d_in[3];
  const float* W0 = (const float*)d_in[4];
  float* out = (float*)d_out;

  char* ws = (char*)d_ws;
  const size_t MB = 1024*1024;
  u16* Xb    = (u16*)(ws);           // 8 MB  [4096][1024]; reused as AO later
  u16* WqkvT = (u16*)(ws +  8*MB);   // 6 MB  [3072][1024] (Wq,Wk,Wv rows)
  u16* W0T   = (u16*)(ws + 14*MB);   // 2 MB
  u16* QKVb  = (u16*)(ws + 16*MB);   // 24 MB [4096][3072] (V third unused)
  u16* Vt    = (u16*)(ws + 40*MB);   // 8 MB  [B*H][64][SEQ] (keys permuted)
  u16* AO    = Xb;                   // Xb dead after QKV GEMM

  const float scaleQ = 1.4426950408889634f / sqrtf((float)SEQ);
  const int M = BATCH*SEQ;

  k_prep<<<dim3(4096 + 1024), 256, 0, stream>>>(
      X, Xb, Wq, Wk, Wv, W0,
      WqkvT, WqkvT + 1024*1024, WqkvT + 2*1024*1024, W0T);
  k_gemm_qkv<<<dim3(3072/128, M/128), 256, 0, stream>>>(
      Xb, WqkvT, QKVb, Vt, scaleQ);
  k_attn<<<dim3(BATCH*NH, SEQ/128), 256, 0, stream>>>(QKVb, Vt, AO);
  k_gemm_out<<<dim3(1024/128, M/64), 256, 0, stream>>>(AO, W0T, out);
}

// Round 18
// 104.606 us; speedup vs baseline: 1.0296x; 1.0296x over previous
//
#include <hip/hip_runtime.h>

#define D_MODEL 1024
#define SEQ     2048
#define BATCH   2
#define NH      16

using u16 = unsigned short;
typedef __bf16 bf16x8 __attribute__((ext_vector_type(8)));
typedef float  f32x4  __attribute__((ext_vector_type(4)));

__device__ __forceinline__ u16 f2bf(float f){
  union { __bf16 h; u16 u; } v; v.h = (__bf16)f; return v.u;
}

__device__ __forceinline__ void gload_lds16(const void* g, void* l){
  __builtin_amdgcn_global_load_lds(
      (const __attribute__((address_space(1))) void*)g,
      (__attribute__((address_space(3))) void*)l, 16, 0, 0);
}

// ---------- kernel 1+2 merged: X fp32->bf16  AND  weights ->bf16 [N][K] ----
__global__ __launch_bounds__(256) void k_prep(
    const float* __restrict__ X, u16* __restrict__ Xb,
    const float* __restrict__ wq, const float* __restrict__ wk,
    const float* __restrict__ wv, const float* __restrict__ w0,
    u16* __restrict__ oq, u16* __restrict__ ok,
    u16* __restrict__ ov, u16* __restrict__ o0)
{
  const int t = threadIdx.x;
  if (blockIdx.x < 4096){
    int i = blockIdx.x*256 + t;
    float4 v = ((const float4*)X)[i];
    ushort4 o; o.x=f2bf(v.x); o.y=f2bf(v.y); o.z=f2bf(v.z); o.w=f2bf(v.w);
    ((ushort4*)Xb)[i] = o;
    return;
  }
  const int bid = blockIdx.x - 4096;
  const int z = bid >> 8, rem = bid & 255;
  const int nt = (rem & 15)*64, kt = (rem >> 4)*64;
  const float* W; u16* O;
  if      (z==0){W=wq;O=oq;}
  else if (z==1){W=wk;O=ok;}
  else if (z==2){W=wv;O=ov;}
  else          {W=w0;O=o0;}
  __shared__ float T[64][65];
  int r0 = t>>4, cb = (t&15)*4;
  #pragma unroll
  for (int j=0;j<4;++j){
    int r = r0 + j*16;
    float4 v = *(const float4*)(W + (size_t)(kt + r)*1024 + nt + cb);
    T[r][cb] = v.x; T[r][cb+1] = v.y; T[r][cb+2] = v.z; T[r][cb+3] = v.w;
  }
  __syncthreads();
  #pragma unroll
  for (int j=0;j<4;++j){
    int rn = r0 + j*16;
    ushort4 o;
    o.x = f2bf(T[cb  ][rn]); o.y = f2bf(T[cb+1][rn]);
    o.z = f2bf(T[cb+2][rn]); o.w = f2bf(T[cb+3][rn]);
    *(ushort4*)(O + (size_t)(nt + rn)*1024 + kt + cb) = o;
  }
}

// ---------- kernel 3: fused QKV GEMM (2-phase dbuf; V fused to Vt) ---------
// 645 TF = the measured 2-phase K=1024 structure ceiling (m248v2). Keep.
__global__ __launch_bounds__(256) void k_gemm_qkv(
    const u16* __restrict__ A, const u16* __restrict__ Bt,
    u16* __restrict__ Ob, u16* __restrict__ Vt, float scaleQ)
{
  const int K = 1024, N = 3072;
  const int nwg = gridDim.x * gridDim.y;
  const int f = blockIdx.y * gridDim.x + blockIdx.x;
  const int sw = (f & 7) * (nwg >> 3) + (f >> 3);
  const int bxs = sw % gridDim.x, bys = sw / gridDim.x;
  const int bm = bys*128, bn = bxs*128;
  const float scl = (bn < 1024) ? scaleQ : 1.0f;
  const int lane = threadIdx.x & 63, w = threadIdx.x >> 6;
  const int hi = lane >> 4, c = lane & 15;
  const int wr = w >> 1, wc = w & 1;

  __shared__ u16 As[2][128*32];
  __shared__ u16 Bs[2][128*32];

  const int i0 = 2*w, i1 = 2*w+1;
  const int rA0 = i0*16 + (lane>>2), rA1 = i1*16 + (lane>>2);
  const int cA  = (lane&3)*8;
  const u16* aS0 = A  + (size_t)(bm + rA0)*K + cA;
  const u16* aS1 = A  + (size_t)(bm + rA1)*K + cA;
  const u16* bS0 = Bt + (size_t)(bn + rA0)*K + cA;
  const u16* bS1 = Bt + (size_t)(bn + rA1)*K + cA;

  auto stage = [&](int buf, int kk){
    gload_lds16(aS0 + kk, As[buf] + i0*512);
    gload_lds16(aS1 + kk, As[buf] + i1*512);
    gload_lds16(bS0 + kk, Bs[buf] + i0*512);
    gload_lds16(bS1 + kk, Bs[buf] + i1*512);
  };

  f32x4 acc[4][4];
  #pragma unroll
  for (int mi=0;mi<4;++mi)
    #pragma unroll
    for (int ni=0;ni<4;++ni) acc[mi][ni] = (f32x4){0.f,0.f,0.f,0.f};

  stage(0, 0);
  __syncthreads();
  int cur = 0;
  for (int kk = 0; kk < K; kk += 32){
    if (kk + 32 < K) stage(cur^1, kk + 32);
    const u16* as = As[cur];
    const u16* bs = Bs[cur];
    bf16x8 af[4], bfr[4];
    #pragma unroll
    for (int mi=0;mi<4;++mi)
      af[mi] = *(const bf16x8*)(as + (wr*64 + mi*16 + c)*32 + hi*8);
    #pragma unroll
    for (int ni=0;ni<4;++ni)
      bfr[ni] = *(const bf16x8*)(bs + (wc*64 + ni*16 + c)*32 + hi*8);
    #pragma unroll
    for (int mi=0;mi<4;++mi)
      #pragma unroll
      for (int ni=0;ni<4;++ni)
        acc[mi][ni] = __builtin_amdgcn_mfma_f32_16x16x32_bf16(af[mi], bfr[ni], acc[mi][ni], 0, 0, 0);
    __syncthreads();
    cur ^= 1;
  }

  if (bn < 2048){
    #pragma unroll
    for (int mi=0;mi<4;++mi){
      #pragma unroll
      for (int ni=0;ni<4;++ni){
        int row = bm + wr*64 + mi*16 + hi*4;
        int col = bn + wc*64 + ni*16 + c;
        #pragma unroll
        for (int r=0;r<4;++r)
          Ob[(size_t)(row + r)*N + col] = f2bf(acc[mi][ni][r] * scl);
      }
    }
  } else {
    // V columns: fused transpose + key-permute into Vt [B*H][64][S-perm]
    #pragma unroll
    for (int mi=0;mi<4;++mi){
      int row = bm + wr*64 + mi*16 + hi*4;           // token s (4-aligned)
      int b_  = row >> 11, s_ = row & 2047;
      int st  = s_ >> 6,  sl = s_ & 63;
      int p   = (sl & 0x23) | ((sl & 0x10) >> 2) | ((sl & 0x0C) << 1);
      #pragma unroll
      for (int ni=0;ni<4;++ni){
        int col = (bn - 2048) + wc*64 + ni*16 + c;    // d_full in [0,1024)
        int h_ = col >> 6, d_ = col & 63;
        u16* dst = Vt + ((size_t)(b_*16 + h_)*64 + d_)*SEQ + st*64 + p;
        ushort4 o;
        o.x = f2bf(acc[mi][ni][0]); o.y = f2bf(acc[mi][ni][1]);
        o.z = f2bf(acc[mi][ni][2]); o.w = f2bf(acc[mi][ni][3]);
        *(ushort4*)dst = o;
      }
    }
  }
}

// ---------- kernel 6: out-proj GEMM (128^2, best measured) -----------------
// R17 lesson: 64x128 (2 blocks/CU) regressed +3us -- per-wave MFMA per
// K-step halves while barrier count stays; 128^2 at 1 block/CU overlaps
// its own 4 waves across the barrier adequately. Keep 128^2.
__global__ __launch_bounds__(256) void k_gemm_out(
    const u16* __restrict__ A, const u16* __restrict__ Bt,
    float* __restrict__ OF)
{
  const int K = 1024, N = 1024;
  const int nwg = gridDim.x * gridDim.y;
  const int f = blockIdx.y * gridDim.x + blockIdx.x;
  const int sw = (f & 7) * (nwg >> 3) + (f >> 3);
  const int bxs = sw % gridDim.x, bys = sw / gridDim.x;
  const int bm = bys*128, bn = bxs*128;
  const int lane = threadIdx.x & 63, w = threadIdx.x >> 6;
  const int hi = lane >> 4, c = lane & 15;
  const int wr = w >> 1, wc = w & 1;

  __shared__ u16 As[2][128*32];
  __shared__ u16 Bs[2][128*32];

  const int i0 = 2*w, i1 = 2*w+1;
  const int rA0 = i0*16 + (lane>>2), rA1 = i1*16 + (lane>>2);
  const int cA  = (lane&3)*8;
  const u16* aS0 = A  + (size_t)(bm + rA0)*K + cA;
  const u16* aS1 = A  + (size_t)(bm + rA1)*K + cA;
  const u16* bS0 = Bt + (size_t)(bn + rA0)*K + cA;
  const u16* bS1 = Bt + (size_t)(bn + rA1)*K + cA;

  auto stage = [&](int buf, int kk){
    gload_lds16(aS0 + kk, As[buf] + i0*512);
    gload_lds16(aS1 + kk, As[buf] + i1*512);
    gload_lds16(bS0 + kk, Bs[buf] + i0*512);
    gload_lds16(bS1 + kk, Bs[buf] + i1*512);
  };

  f32x4 acc[4][4];
  #pragma unroll
  for (int mi=0;mi<4;++mi)
    #pragma unroll
    for (int ni=0;ni<4;++ni) acc[mi][ni] = (f32x4){0.f,0.f,0.f,0.f};

  stage(0, 0);
  __syncthreads();
  int cur = 0;
  for (int kk = 0; kk < K; kk += 32){
    if (kk + 32 < K) stage(cur^1, kk + 32);
    const u16* as = As[cur];
    const u16* bs = Bs[cur];
    bf16x8 af[4], bfr[4];
    #pragma unroll
    for (int mi=0;mi<4;++mi)
      af[mi] = *(const bf16x8*)(as + (wr*64 + mi*16 + c)*32 + hi*8);
    #pragma unroll
    for (int ni=0;ni<4;++ni)
      bfr[ni] = *(const bf16x8*)(bs + (wc*64 + ni*16 + c)*32 + hi*8);
    #pragma unroll
    for (int mi=0;mi<4;++mi)
      #pragma unroll
      for (int ni=0;ni<4;++ni)
        acc[mi][ni] = __builtin_amdgcn_mfma_f32_16x16x32_bf16(af[mi], bfr[ni], acc[mi][ni], 0, 0, 0);
    __syncthreads();
    cur ^= 1;
  }
  #pragma unroll
  for (int mi=0;mi<4;++mi){
    #pragma unroll
    for (int ni=0;ni<4;++ni){
      int row = bm + wr*64 + mi*16 + hi*4;
      int col = bn + wc*64 + ni*16 + c;
      #pragma unroll
      for (int r=0;r<4;++r)
        OF[(size_t)(row + r)*N + col] = acc[mi][ni][r];
    }
  }
}

// ---------- kernel 5: attention (R13 structure -- best measured) -----------
// 4 waves/block (256 thr) = 2 qg x 2 kh; 64 q-rows per wave (4 qsub x 16).
// R14: direct-L2 K/V regressed (LDS staging IS coalescing). R15: 2-wave
// blocks regressed (VGPR 148). grid (bh, qt) head-affine; SWAPPED QK^T;
// exp2 packed as 16x16x32 A-frag; Vt pre-permuted; lsum via ones-MFMA.
__global__ __launch_bounds__(256, 2) void k_attn(const u16* __restrict__ QKV,
                                                 const u16* __restrict__ Vt,
                                                 u16* __restrict__ AO)
{
  const int bh = blockIdx.x, qt = blockIdx.y;
  const int b = bh >> 4, h = bh & 15;
  const int lane = threadIdx.x & 63, w = threadIdx.x >> 6;  // w = 0..3
  const int qg = w >> 1, kh = w & 1;
  const int hi = lane >> 4, c = lane & 15;

  __shared__ u16 Ks[2][64*64];   // [key][dim] rows 128B, source-swizzled
  __shared__ u16 Vs[2][64*64];   // [dim][key'] rows 128B, source-swizzled

  const size_t qrow0 = (size_t)(b*SEQ + qt*128 + qg*64 + c);
  bf16x8 qf0[4], qf1[4];
  #pragma unroll
  for (int s=0;s<4;++s){
    qf0[s] = *(const bf16x8*)(QKV + (qrow0 + s*16)*3072 + h*64 + hi*8);
    qf1[s] = *(const bf16x8*)(QKV + (qrow0 + s*16)*3072 + h*64 + 32 + hi*8);
  }

  bf16x8 ones8;
  #pragma unroll
  for (int j=0;j<8;++j) ones8[j] = (__bf16)1.0f;

  f32x4 acc_o[4][4];
  f32x4 acc_l[4];
  #pragma unroll
  for (int s=0;s<4;++s){
    acc_l[s] = (f32x4){0.f,0.f,0.f,0.f};
    #pragma unroll
    for (int n=0;n<4;++n) acc_o[s][n] = (f32x4){0.f,0.f,0.f,0.f};
  }

  // staging: wave w stages rows w*8..+7 (instr0) and 32+w*8..+7 (instr1)
  const int r0 = w*8 + (lane>>3);
  const int r1 = 32 + r0;
  const int sb = ((((lane&7)*16) ^ ((lane>>3)<<4)) >> 1);  // u16 units
  const u16* kS0 = QKV + (size_t)(b*SEQ + r0)*3072 + 1024 + h*64 + sb;
  const u16* kS1 = QKV + (size_t)(b*SEQ + r1)*3072 + 1024 + h*64 + sb;
  const u16* vS0 = Vt + ((size_t)bh*64 + r0)*SEQ + sb;
  const u16* vS1 = Vt + ((size_t)bh*64 + r1)*SEQ + sb;

  auto stage = [&](int buf){
    gload_lds16(kS0, Ks[buf] + w*512);
    gload_lds16(kS1, Ks[buf] + 2048 + w*512);
    gload_lds16(vS0, Vs[buf] + w*512);
    gload_lds16(vS1, Vs[buf] + 2048 + w*512);
    kS0 += (size_t)64*3072; kS1 += (size_t)64*3072; vS0 += 64; vS1 += 64;
  };

  // hoisted LDS read bases; XOR applied to full byte-within-row offset
  const int swz = ((c&7)<<4);
  const char* kr0 = (const char*)&Ks[0][0] + (kh*32 + c)*128 + (( 0 + hi*16) ^ swz);
  const char* kr1 = (const char*)&Ks[0][0] + (kh*32 + c)*128 + ((64 + hi*16) ^ swz);
  const char* vr  = (const char*)&Vs[0][0] + c*128 + ((kh*64 + hi*16) ^ swz);

  auto body = [&](int buf){
    const int bo = buf*8192;
    bf16x8 k00 = *(const bf16x8*)(kr0 + bo);          // keys t0, dims 0-31
    bf16x8 k01 = *(const bf16x8*)(kr1 + bo);          // keys t0, dims 32-63
    bf16x8 k10 = *(const bf16x8*)(kr0 + bo + 2048);   // keys t1, dims 0-31
    bf16x8 k11 = *(const bf16x8*)(kr1 + bo + 2048);   // keys t1, dims 32-63
    bf16x8 vv0 = *(const bf16x8*)(vr + bo);
    bf16x8 vv1 = *(const bf16x8*)(vr + bo + 2048);
    bf16x8 vv2 = *(const bf16x8*)(vr + bo + 4096);
    bf16x8 vv3 = *(const bf16x8*)(vr + bo + 6144);
    #pragma unroll
    for (int s=0;s<4;++s){
      f32x4 s0 = (f32x4){0.f,0.f,0.f,0.f};
      f32x4 s1 = (f32x4){0.f,0.f,0.f,0.f};
      __builtin_amdgcn_s_setprio(1);
      s0 = __builtin_amdgcn_mfma_f32_16x16x32_bf16(k00, qf0[s], s0, 0,0,0);
      s1 = __builtin_amdgcn_mfma_f32_16x16x32_bf16(k10, qf0[s], s1, 0,0,0);
      s0 = __builtin_amdgcn_mfma_f32_16x16x32_bf16(k01, qf1[s], s0, 0,0,0);
      s1 = __builtin_amdgcn_mfma_f32_16x16x32_bf16(k11, qf1[s], s1, 0,0,0);
      __builtin_amdgcn_s_setprio(0);
      bf16x8 a;
      #pragma unroll
      for (int i=0;i<4;++i){
        a[i]   = (__bf16)__builtin_amdgcn_exp2f(s0[i]);
        a[i+4] = (__bf16)__builtin_amdgcn_exp2f(s1[i]);
      }
      __builtin_amdgcn_s_setprio(1);
      acc_l[s]    = __builtin_amdgcn_mfma_f32_16x16x32_bf16(a, ones8, acc_l[s], 0,0,0);
      acc_o[s][0] = __builtin_amdgcn_mfma_f32_16x16x32_bf16(a, vv0, acc_o[s][0], 0,0,0);
      acc_o[s][1] = __builtin_amdgcn_mfma_f32_16x16x32_bf16(a, vv1, acc_o[s][1], 0,0,0);
      acc_o[s][2] = __builtin_amdgcn_mfma_f32_16x16x32_bf16(a, vv2, acc_o[s][2], 0,0,0);
      acc_o[s][3] = __builtin_amdgcn_mfma_f32_16x16x32_bf16(a, vv3, acc_o[s][3], 0,0,0);
      __builtin_amdgcn_s_setprio(0);
    }
  };

  stage(0);
  __syncthreads();
  #pragma unroll 1
  for (int u = 0; u < SEQ/128; ++u){
    stage(1);
    body(0);
    __syncthreads();
    if (u != SEQ/128 - 1) stage(0);
    body(1);
    __syncthreads();
  }

  // merge key-halves additively, one qsub pass at a time (Of = 8KB in Ks)
  float* Of = (float*)&Ks[0][0];           // [qg][16][64] f32
  float* Lf = (float*)&Vs[0][0];           // [qg][16]
  #pragma unroll
  for (int s=0;s<4;++s){
    if (kh == 1){
      #pragma unroll
      for (int n=0;n<4;++n)
        #pragma unroll
        for (int i=0;i<4;++i)
          Of[qg*1024 + (hi*4+i)*64 + n*16 + c] = acc_o[s][n][i];
      if (c == 0){
        #pragma unroll
        for (int i=0;i<4;++i) Lf[qg*16 + hi*4 + i] = acc_l[s][i];
      }
    }
    __syncthreads();
    if (kh == 0){
      float inv[4];
      #pragma unroll
      for (int i=0;i<4;++i)
        inv[i] = 1.0f / (acc_l[s][i] + Lf[qg*16 + hi*4 + i]);
      size_t obase = (size_t)(b*SEQ + qt*128 + qg*64 + s*16 + hi*4)*D_MODEL + h*64;
      #pragma unroll
      for (int i=0;i<4;++i){
        #pragma unroll
        for (int n=0;n<4;++n){
          float o = acc_o[s][n][i] + Of[qg*1024 + (hi*4+i)*64 + n*16 + c];
          AO[obase + (size_t)i*D_MODEL + n*16 + c] = f2bf(o * inv[i]);
        }
      }
    }
    __syncthreads();
  }
}

extern "C" void kernel_launch(void* const* d_in, const int* in_sizes, int n_in,
                              void* d_out, int out_size, void* d_ws, size_t ws_size,
                              hipStream_t stream)
{
  const float* X  = (const float*)d_in[0];
  const float* Wq = (const float*)d_in[1];
  const float* Wk = (const float*)d_in[2];
  const float* Wv = (const float*)d_in[3];
  const float* W0 = (const float*)d_in[4];
  float* out = (float*)d_out;

  char* ws = (char*)d_ws;
  const size_t MB = 1024*1024;
  u16* Xb    = (u16*)(ws);           // 8 MB  [4096][1024]; reused as AO later
  u16* WqkvT = (u16*)(ws +  8*MB);   // 6 MB  [3072][1024] (Wq,Wk,Wv rows)
  u16* W0T   = (u16*)(ws + 14*MB);   // 2 MB
  u16* QKVb  = (u16*)(ws + 16*MB);   // 24 MB [4096][3072] (V third unused)
  u16* Vt    = (u16*)(ws + 40*MB);   // 8 MB  [B*H][64][SEQ] (keys permuted)
  u16* AO    = Xb;                   // Xb dead after QKV GEMM

  const float scaleQ = 1.4426950408889634f / sqrtf((float)SEQ);
  const int M = BATCH*SEQ;

  k_prep<<<dim3(4096 + 1024), 256, 0, stream>>>(
      X, Xb, Wq, Wk, Wv, W0,
      WqkvT, WqkvT + 1024*1024, WqkvT + 2*1024*1024, W0T);
  k_gemm_qkv<<<dim3(3072/128, M/128), 256, 0, stream>>>(
      Xb, WqkvT, QKVb, Vt, scaleQ);
  k_attn<<<dim3(BATCH*NH, SEQ/128), 256, 0, stream>>>(QKVb, Vt, AO);
  k_gemm_out<<<dim3(1024/128, M/128), 256, 0, stream>>>(AO, W0T, out);
}